// Round 14
// baseline (211.381 us; speedup 1.0000x reference)
//
#include <hip/hip_runtime.h>
#include <hip/hip_bf16.h>
#include <hip/hip_fp16.h>

#define NN 100000
#define NE 3200000
#define IN_F 128
#define HID 32

#define BNODES 131      // nodes per bucket
#define NB 764          // ceil(NN/BNODES) -> ~3.0 blocks/CU on 256 CUs
#define NBP1 (NB + 1)
#define PBLK 768        // partition blocks -> 3.0 blocks/CU
#define EPB 4168        // ceil(NE/PBLK) edges per partition block (even)
#define SSPAN 4736      // per-bucket span bound: mean 4188 + 8 sigma (65)

typedef __hip_bfloat16 bf16;
typedef __attribute__((ext_vector_type(8))) short s16x8;   // 8 bf16 (4 VGPRs)
typedef __attribute__((ext_vector_type(4))) float f32x4;   // MFMA C/D

// bf16 (as ushort bits) -> f32 is an exact 16-bit left shift
__device__ __forceinline__ float bf2f(unsigned short u) {
    return __uint_as_float((unsigned)u << 16);
}

// ---------------- partition: LDS counting sort, ALL global writes dense ----------------
__global__ __launch_bounds__(512) void k_part(const int* __restrict__ ei,
                                              const float* __restrict__ ew,
                                              int* __restrict__ offs,
                                              uint2* __restrict__ raw) {
    __shared__ int hist[NB];
    __shared__ int start[NB];
    __shared__ int wtot8[8];
    __shared__ __align__(16) uint2 sp[EPB];   // 33.3 KB

    int t = threadIdx.x;
    int blk = blockIdx.x;
    for (int b = t; b < NB; b += 512) hist[b] = 0;
    __syncthreads();

    unsigned pk[10]; unsigned wb[10]; int bkt[10];
    int base_e = blk * EPB;
#pragma unroll
    for (int j = 0; j < 5; j++) {
        int p = j * 512 + t;               // pair index within block
        int e = base_e + 2 * p;
        bool v = (p < (EPB / 2)) && (e < NE);
        if (v) {
            int2   s2 = *(const int2*)(ei + e);
            int2   d2 = *(const int2*)(ei + NE + e);
            float2 w2 = *(const float2*)(ew + e);
            int bk0 = d2.x / BNODES;           // magic-mul by compiler
            bkt[2 * j]     = bk0;
            pk[2 * j]      = (unsigned)s2.x | ((unsigned)(d2.x - bk0 * BNODES) << 20);
            wb[2 * j]      = __float_as_uint(w2.x);
            int bk1 = d2.y / BNODES;
            bkt[2 * j + 1] = bk1;
            pk[2 * j + 1]  = (unsigned)s2.y | ((unsigned)(d2.y - bk1 * BNODES) << 20);
            wb[2 * j + 1]  = __float_as_uint(w2.y);
        } else { bkt[2 * j] = -1; bkt[2 * j + 1] = -1; }
    }
#pragma unroll
    for (int j = 0; j < 10; j++)
        if (bkt[j] >= 0) atomicAdd(&hist[bkt[j]], 1);
    __syncthreads();

    // exclusive scan over 764 bins (2 per thread, shuffle-based)
    int e0 = 2 * t, e1 = 2 * t + 1;
    int h0 = (e0 < NB) ? hist[e0] : 0;
    int h1 = (e1 < NB) ? hist[e1] : 0;
    int psum = h0 + h1;
    int lane = t & 63;
    int incl = psum;
#pragma unroll
    for (int off = 1; off < 64; off <<= 1) {
        int up = __shfl_up(incl, off, 64);
        if (lane >= off) incl += up;
    }
    int wid = t >> 6;
    if (lane == 63) wtot8[wid] = incl;
    __syncthreads();
    int woff = 0;
    for (int wj = 0; wj < wid; wj++) woff += wtot8[wj];
    int exc = woff + incl - psum;
    if (e0 < NB) start[e0] = exc;
    if (e1 < NB) start[e1] = exc + h0;
    __syncthreads();

    int total = start[NB - 1] + hist[NB - 1];
    int* orow = offs + (size_t)blk * NBP1;
    for (int b = t; b < NB; b += 512) orow[b] = start[b];
    if (t == 0) orow[NB] = total;
    __syncthreads();   // orow reads of start[] complete before cursor mutation

    // LDS counting scatter (start[] becomes cursor)
#pragma unroll
    for (int j = 0; j < 10; j++) {
        if (bkt[j] >= 0) {
            int pos = atomicAdd(&start[bkt[j]], 1);
            sp[pos] = make_uint2(pk[j], wb[j]);
        }
    }
    __syncthreads();

    // dense, coalesced 16B copy to block-private region (written exactly once)
    uint2* r = raw + (size_t)blk * EPB;
    int tot2 = total >> 1;
    const uint4* sp4 = (const uint4*)sp;
    uint4* r4 = (uint4*)r;
    for (int i = t; i < tot2; i += 512) r4[i] = sp4[i];
    if (t == 0 && (total & 1)) r[total - 1] = sp[total - 1];
}

// ---------------- offs transpose ([blk][bucket] -> [bucket][blk]) ----------------
__global__ __launch_bounds__(256) void k_trans(const int* __restrict__ in, int* __restrict__ out) {
    __shared__ int tile[32][33];
    int c0 = blockIdx.x * 32, r0 = blockIdx.y * 32;
    int tx = threadIdx.x & 31, ty = threadIdx.x >> 5;   // 32 x 8
    for (int i = ty; i < 32; i += 8) {
        int r = r0 + i, c = c0 + tx;
        if (r < PBLK && c < NBP1) tile[i][tx] = in[(size_t)r * NBP1 + c];
    }
    __syncthreads();
    for (int i = ty; i < 32; i += 8) {
        int c = c0 + i, r = r0 + tx;
        if (c < NBP1 && r < PBLK) out[(size_t)c * PBLK + r] = tile[tx][i];
    }
}

// ---------------- fused per-bucket: degree -> dinv -> hs = dinv*(x@W1) via MFMA ----------
// hs stored as TWO PLANES of [NN][16] bf16 (3.2 MB each, L2-resident per plane):
// plane 0 = features 0..15 (acc0), plane 1 = features 16..31 (acc1).
__global__ __launch_bounds__(512) void k_dh(const int* __restrict__ offsT,
                                            const uint2* __restrict__ raw,
                                            const float* __restrict__ x,
                                            const float* __restrict__ W1,
                                            float* __restrict__ dinv,
                                            bf16* __restrict__ hs) {
    __shared__ unsigned short runid[SSPAN];   //  9.5 KB
    __shared__ int P[PBLK + 1];               //  3.1 KB
    __shared__ int basearr[PBLK];             //  3.1 KB
    __shared__ float wsumf[BNODES];
    __shared__ float dinvl[BNODES];
    __shared__ int wt8[8];

    int t = threadIdx.x;
    int b = blockIdx.x;
    if (t < BNODES) wsumf[t] = 0.f;

    int e0 = 2 * t, e1 = 2 * t + 1;
    int l0 = 0, l1 = 0, o0v = 0, o1v = 0;
    if (e0 < PBLK) {
        o0v = offsT[(size_t)b * PBLK + e0];
        l0  = offsT[(size_t)(b + 1) * PBLK + e0] - o0v;
    }
    if (e1 < PBLK) {
        o1v = offsT[(size_t)b * PBLK + e1];
        l1  = offsT[(size_t)(b + 1) * PBLK + e1] - o1v;
    }
    int psum = l0 + l1;
    int lane = t & 63;
    int incl = psum;
#pragma unroll
    for (int off = 1; off < 64; off <<= 1) {
        int up = __shfl_up(incl, off, 64);
        if (lane >= off) incl += up;
    }
    int wid = t >> 6;
    if (lane == 63) wt8[wid] = incl;
    __syncthreads();          // covers wsum init
    int woff = 0;
    for (int wj = 0; wj < wid; wj++) woff += wt8[wj];
    int exc = woff + incl - psum;
    if (e0 < PBLK) { P[e0] = exc;      basearr[e0] = o0v - exc; }
    if (e1 < PBLK) { P[e1] = exc + l0; basearr[e1] = o1v - (exc + l0); }
    if (t == 0) {
        int s = 0;
#pragma unroll
        for (int j = 0; j < 8; j++) s += wt8[j];
        P[PBLK] = s;
    }
    __syncthreads();

    int total = min(P[PBLK], SSPAN);

    for (int r = t; r < PBLK; r += 512) {
        int p0 = P[r], p1 = min(P[r + 1], SSPAN);
        for (int i = p0; i < p1; i++) runid[i] = (unsigned short)r;
    }
    __syncthreads();

#pragma unroll
    for (int k = 0; k < 10; k++) {
        int d = t + k * 512;
        if (d < total) {
            int r = runid[d];
            uint2 rec = raw[(size_t)r * EPB + (basearr[r] + d)];
            atomicAdd(&wsumf[(rec.x >> 20) & 255], __uint_as_float(rec.y));
        }
    }
    __syncthreads();

    if (t < BNODES) {
        float dv = rsqrtf(wsumf[t] + 1.0f);   // +1 = self-loop
        dinvl[t] = dv;
        int node = b * BNODES + t;
        if (node < NN) dinv[node] = dv;
    }
    __syncthreads();

    // ---- phase B: MFMA hs for this bucket's contiguous node range ----
    int wv = t >> 6;          // wave 0..7
    int m = lane & 15;
    int q = lane >> 4;

    // W1 -> B-fragments, inline
    s16x8 wf[8];
    {
#pragma unroll
        for (int ks2 = 0; ks2 < 4; ks2++) {
#pragma unroll
            for (int nt = 0; nt < 2; nt++) {
                union { s16x8 v; unsigned short u[8]; } wu;
#pragma unroll
                for (int j = 0; j < 8; j++) {
                    int kk = ks2 * 32 + q * 8 + j;
                    __hip_bfloat16 bv = __float2bfloat16(W1[kk * HID + m + 16 * nt]);
                    wu.u[j] = *(unsigned short*)&bv;
                }
                wf[ks2 * 2 + nt] = wu.v;
            }
        }
    }

    // 9 tiles of 16 rows cover 131 local nodes; waves take tile = wv, wv+8
    for (int tile = wv; tile * 16 < BNODES; tile += 8) {
        int lrow = tile * 16 + m;             // local row this lane loads
        int node = b * BNODES + lrow;
        bool valid = (lrow < BNODES) && (node < NN);

        f32x4 acc0 = {0.f, 0.f, 0.f, 0.f};
        f32x4 acc1 = {0.f, 0.f, 0.f, 0.f};
        const float* rowp = x + (size_t)node * IN_F + q * 8;

#pragma unroll
        for (int ks = 0; ks < 4; ks++) {
            float4 f0 = {0,0,0,0}, f1 = {0,0,0,0};
            if (valid) {
                const float4* xr = (const float4*)(rowp + ks * 32);
                f0 = xr[0]; f1 = xr[1];
            }
            union { s16x8 v; unsigned u32[4]; } af;
            __hip_bfloat162 p0 = __float22bfloat162_rn({f0.x, f0.y});
            __hip_bfloat162 p1 = __float22bfloat162_rn({f0.z, f0.w});
            __hip_bfloat162 p2 = __float22bfloat162_rn({f1.x, f1.y});
            __hip_bfloat162 p3 = __float22bfloat162_rn({f1.z, f1.w});
            af.u32[0] = *(unsigned*)&p0;
            af.u32[1] = *(unsigned*)&p1;
            af.u32[2] = *(unsigned*)&p2;
            af.u32[3] = *(unsigned*)&p3;
            acc0 = __builtin_amdgcn_mfma_f32_16x16x32_bf16(af.v, wf[ks * 2 + 0], acc0, 0, 0, 0);
            acc1 = __builtin_amdgcn_mfma_f32_16x16x32_bf16(af.v, wf[ks * 2 + 1], acc1, 0, 0, 0);
        }

        int f = m;
#pragma unroll
        for (int r = 0; r < 4; r++) {
            int l2 = tile * 16 + q * 4 + r;   // local row this lane writes
            int n2 = b * BNODES + l2;
            if (l2 < BNODES && n2 < NN) {
                float dv = dinvl[l2];
                hs[(size_t)n2 * 16 + f]        = __float2bfloat16(dv * acc0[r]);  // plane 0
                hs[(size_t)(NN + n2) * 16 + f] = __float2bfloat16(dv * acc1[r]);  // plane 1
            }
        }
    }
}

// ---------------- fused: per-bucket gather + LDS counting sort + register pull + epilogue ----
// Phase B runs TWO temporal feature-half passes so each pass gathers from a 3.2-MB
// L2-resident plane. Half-0's ReLU+W2 partial dot collapses to one float/node (pspart).
__global__ __launch_bounds__(512) void k_agg(const int* __restrict__ offsT,
                                             const uint2* __restrict__ raw,
                                             const bf16* __restrict__ hs,
                                             const float* __restrict__ dinv,
                                             const float* __restrict__ b1, const float* __restrict__ W2,
                                             const float* __restrict__ b2, float* __restrict__ out) {
    __shared__ uint2 se[SSPAN];               // 37.9 KB; aliased by runid in phase A
    __shared__ int P[PBLK + 1];               //  3.1 KB
    __shared__ int basearr[PBLK];             //  3.1 KB
    __shared__ int hist[BNODES];
    __shared__ int scanbuf[BNODES];
    __shared__ int cur[BNODES];
    __shared__ float pspart[BNODES];          //  524 B: half-0 partial W2-dot per node
    __shared__ int wt8[8];

    unsigned short* runid = (unsigned short*)se;   // dead before se is written

    int t = threadIdx.x;
    int b = blockIdx.x;
    if (t < BNODES) hist[t] = 0;

    int e0 = 2 * t, e1 = 2 * t + 1;
    int l0 = 0, l1 = 0, o0v = 0, o1v = 0;
    if (e0 < PBLK) {
        o0v = offsT[(size_t)b * PBLK + e0];
        l0  = offsT[(size_t)(b + 1) * PBLK + e0] - o0v;
    }
    if (e1 < PBLK) {
        o1v = offsT[(size_t)b * PBLK + e1];
        l1  = offsT[(size_t)(b + 1) * PBLK + e1] - o1v;
    }
    int psum = l0 + l1;
    int lane = t & 63;
    int incl = psum;
#pragma unroll
    for (int off = 1; off < 64; off <<= 1) {
        int up = __shfl_up(incl, off, 64);
        if (lane >= off) incl += up;
    }
    int wid = t >> 6;
    if (lane == 63) wt8[wid] = incl;
    __syncthreads();
    int woff = 0;
    for (int wj = 0; wj < wid; wj++) woff += wt8[wj];
    int exc = woff + incl - psum;
    if (e0 < PBLK) { P[e0] = exc;      basearr[e0] = o0v - exc; }
    if (e1 < PBLK) { P[e1] = exc + l0; basearr[e1] = o1v - (exc + l0); }
    if (t == 0) {
        int s = 0;
#pragma unroll
        for (int j = 0; j < 8; j++) s += wt8[j];
        P[PBLK] = s;
    }
    __syncthreads();

    int total = min(P[PBLK], SSPAN);

    for (int r = t; r < PBLK; r += 512) {
        int p0 = P[r], p1 = min(P[r + 1], SSPAN);
        for (int i = p0; i < p1; i++) runid[i] = (unsigned short)r;
    }
    __syncthreads();

    // pass 1: coalesced gather into REGISTERS + node histogram (<=10 recs/thread)
    uint2 rr[10];
#pragma unroll
    for (int k = 0; k < 10; k++) {
        int d = t + k * 512;
        if (d < total) {
            int r = runid[d];
            uint2 rec = raw[(size_t)r * EPB + (basearr[r] + d)];
            rr[k] = rec;
            int dl = (rec.x >> 20) & 255;
            atomicAdd(&hist[dl], 1);
        }
    }
    __syncthreads();   // runid dead from here; se region reusable

    // inclusive scan of node hist (Hillis-Steele over 131)
    if (t < BNODES) scanbuf[t] = hist[t];
    __syncthreads();
    for (int off = 1; off < BNODES; off <<= 1) {
        int v = 0;
        if (t < BNODES && t >= off) v = scanbuf[t - off];
        __syncthreads();
        if (t < BNODES) scanbuf[t] += v;
        __syncthreads();
    }
    if (t < BNODES) cur[t] = scanbuf[t] - hist[t];   // exclusive start
    __syncthreads();

    // pass 2: scatter from registers into se at final sorted positions
#pragma unroll
    for (int k = 0; k < 10; k++) {
        int d = t + k * 512;
        if (d < total) {
            uint2 rec = rr[k];
            int dl = (rec.x >> 20) & 255;
            int pos = atomicAdd(&cur[dl], 1);   // LDS int atomic
            se[pos] = make_uint2(rec.x & 0xFFFFF, rec.y);
        }
    }
    __syncthreads();

    // ---- phase B: two feature-half passes over L2-resident hs planes ----
    int gid = t >> 4;          // 0..31, 16 lanes each
    int l = t & 15;
    const unsigned short* hsu = (const unsigned short*)hs;
#pragma unroll
    for (int h = 0; h < 2; h++) {
        const unsigned short* hsh = hsu + (size_t)h * NN * 16;
        for (int dl = gid; dl < BNODES; dl += 32) {
            int cnt = hist[dl];
            int rs = scanbuf[dl] - cnt;
            float a = 0.f;
            int full = cnt & ~7;
            int bse = 0;
            for (; bse < full; bse += 8) {
                uint2 q0 = se[rs + bse + 0];
                uint2 q1 = se[rs + bse + 1];
                uint2 q2 = se[rs + bse + 2];
                uint2 q3 = se[rs + bse + 3];
                uint2 q4 = se[rs + bse + 4];
                uint2 q5 = se[rs + bse + 5];
                uint2 q6 = se[rs + bse + 6];
                uint2 q7 = se[rs + bse + 7];
                float h0 = bf2f(hsh[(size_t)q0.x * 16 + l]);
                float h1 = bf2f(hsh[(size_t)q1.x * 16 + l]);
                float h2 = bf2f(hsh[(size_t)q2.x * 16 + l]);
                float h3 = bf2f(hsh[(size_t)q3.x * 16 + l]);
                float h4 = bf2f(hsh[(size_t)q4.x * 16 + l]);
                float h5 = bf2f(hsh[(size_t)q5.x * 16 + l]);
                float h6 = bf2f(hsh[(size_t)q6.x * 16 + l]);
                float h7 = bf2f(hsh[(size_t)q7.x * 16 + l]);
                a += __uint_as_float(q0.y) * h0;
                a += __uint_as_float(q1.y) * h1;
                a += __uint_as_float(q2.y) * h2;
                a += __uint_as_float(q3.y) * h3;
                a += __uint_as_float(q4.y) * h4;
                a += __uint_as_float(q5.y) * h5;
                a += __uint_as_float(q6.y) * h6;
                a += __uint_as_float(q7.y) * h7;
            }
            if (bse < cnt) {
                int rem = cnt - bse;   // 1..7
                uint2 q0 = se[rs + bse];
                uint2 q1 = se[rs + bse + (rem > 1 ? 1 : 0)];
                uint2 q2 = se[rs + bse + (rem > 2 ? 2 : 0)];
                uint2 q3 = se[rs + bse + (rem > 3 ? 3 : 0)];
                uint2 q4 = se[rs + bse + (rem > 4 ? 4 : 0)];
                uint2 q5 = se[rs + bse + (rem > 5 ? 5 : 0)];
                uint2 q6 = se[rs + bse + (rem > 6 ? 6 : 0)];
                float w0 = __uint_as_float(q0.y);
                float w1 = rem > 1 ? __uint_as_float(q1.y) : 0.f;
                float w2 = rem > 2 ? __uint_as_float(q2.y) : 0.f;
                float w3 = rem > 3 ? __uint_as_float(q3.y) : 0.f;
                float w4 = rem > 4 ? __uint_as_float(q4.y) : 0.f;
                float w5 = rem > 5 ? __uint_as_float(q5.y) : 0.f;
                float w6 = rem > 6 ? __uint_as_float(q6.y) : 0.f;
                a += w0 * bf2f(hsh[(size_t)q0.x * 16 + l]);
                a += w1 * bf2f(hsh[(size_t)q1.x * 16 + l]);
                a += w2 * bf2f(hsh[(size_t)q2.x * 16 + l]);
                a += w3 * bf2f(hsh[(size_t)q3.x * 16 + l]);
                a += w4 * bf2f(hsh[(size_t)q4.x * 16 + l]);
                a += w5 * bf2f(hsh[(size_t)q5.x * 16 + l]);
                a += w6 * bf2f(hsh[(size_t)q6.x * 16 + l]);
            }
            int node = b * BNODES + dl;
            if (node < NN) {
                float dv = dinv[node];
                float fs = bf2f(hsh[(size_t)node * 16 + l]);   // scaled self term, this half
                float v = dv * (a + fs) + b1[h * 16 + l];
                v = fmaxf(v, 0.f);
                float ps = v * W2[h * 16 + l];
#pragma unroll
                for (int m2 = 8; m2 >= 1; m2 >>= 1) ps += __shfl_xor(ps, m2, 16);
                if (l == 0) {
                    if (h == 0) pspart[dl] = ps;               // same thread reads it in h=1
                    else        out[node] = ps + pspart[dl] + b2[0];
                }
            }
        }
    }
}

// ---------------- launch ----------------
extern "C" void kernel_launch(void* const* d_in, const int* in_sizes, int n_in,
                              void* d_out, int out_size, void* d_ws, size_t ws_size,
                              hipStream_t stream) {
    const float* x  = (const float*)d_in[0];
    const int*   ei = (const int*)d_in[1];
    const float* ew = (const float*)d_in[2];
    const float* W1 = (const float*)d_in[3];
    const float* b1 = (const float*)d_in[4];
    const float* W2 = (const float*)d_in[5];
    const float* b2 = (const float*)d_in[6];
    float* out = (float*)d_out;

    char* ws = (char*)d_ws;
    // ws layout (bytes), total ~37.1 MB.
    uint2* raw   = (uint2*)(ws + 0);           // PBLK*EPB uint2 = 25,608,192
    int*   offs  = (int*)  (ws + 25608192);    // PBLK*NBP1 int = 2,350,080 -> 27,958,272
    int*   offsT = (int*)  (ws + 27958272);    // NBP1*PBLK int = 2,350,080 -> 30,308,352
    bf16*  hs    = (bf16*) (ws + 30308352);    // 2 planes x NN x 16 bf16 = 6,400,000 -> 36,708,352
    float* dinv  = (float*)(ws + 36708352);    // NN floats -> 37,108,352

    k_part<<<PBLK, 512, 0, stream>>>(ei, ew, offs, raw);
    k_trans<<<dim3((NBP1 + 31) / 32, (PBLK + 31) / 32), 256, 0, stream>>>(offs, offsT);
    k_dh<<<NB, 512, 0, stream>>>(offsT, raw, x, W1, dinv, hs);
    k_agg<<<NB, 512, 0, stream>>>(offsT, raw, hs, dinv, b1, W2, b2, out);
}